// Round 3
// baseline (1078.473 us; speedup 1.0000x reference)
//
#include <hip/hip_runtime.h>
#include <math.h>

#define IND  64
#define OUTD 101

__device__ __forceinline__ void finish_row(
    float acc0, float acc1, int row, int lane,
    const float* __restrict__ t, float ngf,
    float* __restrict__ out1, float* __restrict__ out_interp)
{
    const int jB = lane + 64;
    // wave-wide softmax over the 101 (padded to 128) logits
    float m = fmaxf(acc0, acc1);
#pragma unroll
    for (int s = 32; s > 0; s >>= 1) m = fmaxf(m, __shfl_xor(m, s, 64));
    float p0 = __expf(acc0 - m);
    float p1 = __expf(acc1 - m);   // 0 for padded columns (acc1 = -inf)
    float ssum = p0 + p1;
#pragma unroll
    for (int s = 32; s > 0; s >>= 1) ssum += __shfl_xor(ssum, s, 64);
    float inv = __builtin_amdgcn_rcpf(ssum);
    inv = inv * (2.0f - ssum * inv);   // one Newton step -> ~fp32 exact
    p0 *= inv;
    p1 *= inv;

    // coalesced out1 row store (404 B contiguous)
    float* orow = out1 + (size_t)row * OUTD;
    orow[lane] = p0;
    if (jB < OUTD) orow[jB] = p1;

    // data-dependent dual gather + lerp (indices wave-uniform)
    const float tB    = t[row] * ngf;
    const float U     = ceilf(tB);
    const float inter = 1.0f - (U - tB);
    float L = U - 1.0f;
    if (L < 0.0f) L += 1.0f;
    const int Li = (int)L;
    const int Ui = (int)U;
    const float srcL = (Li >= 64) ? p1 : p0;   // uniform select
    const float Lval = __shfl(srcL, Li & 63, 64);
    const float srcU = (Ui >= 64) ? p1 : p0;
    const float Uval = __shfl(srcU, Ui & 63, 64);
    if (lane == 0) out_interp[row] = Lval + (Uval - Lval) * inter;
}

// (64, 2): cap 256 VGPR so the 128 pinned weight regs fit without spill.
__global__ __launch_bounds__(64, 2) void density_kernel(
    const float* __restrict__ t,
    const float* __restrict__ x,
    const float* __restrict__ weight,
    const float* __restrict__ bias,
    const int*   __restrict__ num_grid,
    float* __restrict__ out1,
    float* __restrict__ out_interp,
    int n_rows, int n_blocks)
{
    const int lane = threadIdx.x;      // 0..63, lane == column slot A
    const int jB   = lane + 64;        // column slot B (may be >= OUTD)
    const float ngf = (float)num_grid[0];

    // Load weight columns, then PIN them in VGPRs: the empty asm makes each
    // value opaque so the compiler cannot sink/rematerialize the global load
    // into the row loop (which is what kept VGPR_Count at 76 in rounds 1-2).
    float w0[IND], w1[IND];
#pragma unroll
    for (int k = 0; k < IND; ++k) {
        w0[k] = weight[k * OUTD + lane];
        w1[k] = (jB < OUTD) ? weight[k * OUTD + jB] : 0.0f;
    }
#pragma unroll
    for (int k = 0; k < IND; ++k) {
        asm volatile("" : "+v"(w0[k]), "+v"(w1[k]));
    }
    const float b0 = bias[lane];
    const float b1 = (jB < OUTD) ? bias[jB] : -INFINITY;  // exp -> 0

    // 2-row unroll: two independent x streams (s_loads) + two FMA chains in
    // flight per wave to hide the ~900-cyc HBM latency of streaming x.
    for (int row = blockIdx.x; row < n_rows; row += 2 * n_blocks) {
        const int  rowB  = row + n_blocks;
        const bool hasB  = (rowB < n_rows);
        const float* xrA = x + (size_t)row * IND;
        const float* xrB = x + (size_t)(hasB ? rowB : row) * IND;

        float a0 = b0, a1 = b1;
        float c0 = b0, c1 = b1;
#pragma unroll
        for (int k = 0; k < IND; ++k) {
            const float xa = xrA[k];
            a0 = fmaf(xa, w0[k], a0);
            a1 = fmaf(xa, w1[k], a1);
            const float xb = xrB[k];
            c0 = fmaf(xb, w0[k], c0);
            c1 = fmaf(xb, w1[k], c1);
        }

        finish_row(a0, a1, row, lane, t, ngf, out1, out_interp);
        if (hasB) finish_row(c0, c1, rowB, lane, t, ngf, out1, out_interp);
    }
}

extern "C" void kernel_launch(void* const* d_in, const int* in_sizes, int n_in,
                              void* d_out, int out_size, void* d_ws, size_t ws_size,
                              hipStream_t stream) {
    const float* t  = (const float*)d_in[0];
    const float* x  = (const float*)d_in[1];
    const float* w  = (const float*)d_in[2];
    const float* b  = (const float*)d_in[3];
    const int*   ng = (const int*)d_in[4];
    const int n_rows = in_sizes[0];

    float* out1       = (float*)d_out;
    float* out_interp = out1 + (size_t)n_rows * OUTD;

    // 2 waves/SIMD x 4 SIMD x 256 CU = 2048 resident one-wave blocks
    const int n_blocks = 2048;
    density_kernel<<<dim3(n_blocks), dim3(64), 0, stream>>>(
        t, x, w, b, ng, out1, out_interp, n_rows, n_blocks);
}

// Round 4
// 431.467 us; speedup vs baseline: 2.4996x; 2.4996x over previous
//
#include <hip/hip_runtime.h>
#include <hip/hip_fp16.h>
#include <math.h>

#define IND   64
#define OUTD  101
#define RPB   64            // rows per block = one wave
#define ROW_H 128           // fp16 slots per LDS row: 16 blocks x 8
#define NEG_BIG -60000.0f

__global__ __launch_bounds__(64, 2) void density_kernel(
    const float* __restrict__ t,
    const float* __restrict__ x,
    const float* __restrict__ weight,
    const float* __restrict__ bias,
    const int*   __restrict__ num_grid,
    float* __restrict__ out1,
    float* __restrict__ out_interp,
    int n_rows)
{
    __shared__ unsigned short tile[RPB * ROW_H];   // 16 KiB, fp16 logits
    __shared__ float2 ms[RPB];                     // per-row (max, 1/sum)

    const int lane = threadIdx.x;                  // 0..63 = row within tile
    const int row0 = blockIdx.x * RPB;
    const int row  = row0 + lane;
    const int rc   = (row < n_rows) ? row : (n_rows - 1);
    const int sw   = lane & 7;                     // LDS swizzle key

    // ---- x row -> 64 registers (fully static indexing) ----
    const float4* xr4 = (const float4*)(x + (size_t)rc * IND);
    float xv[IND];
#pragma unroll
    for (int q = 0; q < IND / 4; ++q) {
        const float4 v = xr4[q];
        xv[4*q+0] = v.x; xv[4*q+1] = v.y; xv[4*q+2] = v.z; xv[4*q+3] = v.w;
    }

    float m_run = -INFINITY, s_run = 0.0f;

    // ---- 12 full chunks of 8 columns: logits + online max/sum ----
#pragma unroll 1
    for (int ci = 0; ci < 12; ++ci) {
        const int j0 = ci * 8;
        float acc[8];
#pragma unroll
        for (int jc = 0; jc < 8; ++jc) acc[jc] = bias[j0 + jc];   // uniform -> s_load
#pragma unroll
        for (int k = 0; k < IND; ++k) {
            const float* wk = weight + k * OUTD + j0;             // uniform -> s_load_dwordx8
#pragma unroll
            for (int jc = 0; jc < 8; ++jc)
                acc[jc] = fmaf(xv[k], wk[jc], acc[jc]);
        }
        const float cmax = fmaxf(fmaxf(fmaxf(acc[0],acc[1]), fmaxf(acc[2],acc[3])),
                                 fmaxf(fmaxf(acc[4],acc[5]), fmaxf(acc[6],acc[7])));
        const float mnew = fmaxf(m_run, cmax);
        float sadd = 0.0f;
#pragma unroll
        for (int jc = 0; jc < 8; ++jc) sadd += __expf(acc[jc] - mnew);
        s_run = s_run * __expf(m_run - mnew) + sadd;   // first iter: exp(-inf)=0
        m_run = mnew;

        __half2 h0 = __floats2half2_rn(acc[0], acc[1]);
        __half2 h1 = __floats2half2_rn(acc[2], acc[3]);
        __half2 h2 = __floats2half2_rn(acc[4], acc[5]);
        __half2 h3 = __floats2half2_rn(acc[6], acc[7]);
        uint4 pk;
        pk.x = *(unsigned*)&h0; pk.y = *(unsigned*)&h1;
        pk.z = *(unsigned*)&h2; pk.w = *(unsigned*)&h3;
        *(uint4*)&tile[lane * ROW_H + ((ci ^ sw) << 3)] = pk;      // swizzled, 16B aligned
    }

    // ---- tail chunk: compute cols 93..100, keep 96..100 (pad 101..103 = -big) ----
    {
        const int j0 = 93;
        float acc[8];
#pragma unroll
        for (int jc = 0; jc < 8; ++jc) acc[jc] = bias[j0 + jc];
#pragma unroll
        for (int k = 0; k < IND; ++k) {
            const float* wk = weight + k * OUTD + j0;
#pragma unroll
            for (int jc = 0; jc < 8; ++jc)
                acc[jc] = fmaf(xv[k], wk[jc], acc[jc]);
        }
        const float cmax = fmaxf(fmaxf(acc[3], acc[4]),
                                 fmaxf(fmaxf(acc[5], acc[6]), acc[7]));
        const float mnew = fmaxf(m_run, cmax);
        float sadd = 0.0f;
#pragma unroll
        for (int jc = 3; jc < 8; ++jc) sadd += __expf(acc[jc] - mnew);  // cols 96..100 only
        s_run = s_run * __expf(m_run - mnew) + sadd;
        m_run = mnew;

        __half2 h0 = __floats2half2_rn(acc[3], acc[4]);   // cols 96,97
        __half2 h1 = __floats2half2_rn(acc[5], acc[6]);   // cols 98,99
        __half2 h2 = __floats2half2_rn(acc[7], NEG_BIG);  // col 100, pad
        __half2 h3 = __floats2half2_rn(NEG_BIG, NEG_BIG); // pad
        uint4 pk;
        pk.x = *(unsigned*)&h0; pk.y = *(unsigned*)&h1;
        pk.z = *(unsigned*)&h2; pk.w = *(unsigned*)&h3;
        *(uint4*)&tile[lane * ROW_H + ((12 ^ sw) << 3)] = pk;
    }

    // per-row 1/sum (Newton-refined rcp)
    float inv = __builtin_amdgcn_rcpf(s_run);
    inv = inv * (2.0f - s_run * inv);
    ms[lane] = make_float2(m_run, inv);

    // ---- interp output (thread owns its row; reads only its own LDS row) ----
    {
        const float ngf = (float)num_grid[0];
        const float tB    = t[rc] * ngf;
        const float U     = ceilf(tB);
        const float inter = 1.0f - (U - tB);
        float L = U - 1.0f;
        if (L < 0.0f) L += 1.0f;
        const int Li = (int)L;
        const int Ui = (int)U;

        int bL = Li >> 3, oL = Li & 7;
        unsigned short hL = tile[lane * ROW_H + (((bL ^ sw)) << 3) + oL];
        int bU = Ui >> 3, oU = Ui & 7;
        unsigned short hU = tile[lane * ROW_H + (((bU ^ sw)) << 3) + oU];
        const float Lv = __expf(__half2float(*(__half*)&hL) - m_run) * inv;
        const float Uv = __expf(__half2float(*(__half*)&hU) - m_run) * inv;
        if (row < n_rows)
            out_interp[row] = Lv + (Uv - Lv) * inter;
    }

    __syncthreads();

    // ---- phase 4: transposed read, normalize, coalesced out1 stores ----
#pragma unroll 1
    for (int r = 0; r < RPB; ++r) {
        const int gr = row0 + r;
        if (gr >= n_rows) break;
        const float2 msr = ms[r];                 // wave-uniform broadcast
        const int c0   = 2 * lane;                // cols c0, c0+1
        const int b    = c0 >> 3;
        const int phys = b ^ (r & 7);
        const unsigned u =
            *(const unsigned*)&tile[r * ROW_H + (phys << 3) + (c0 & 7)];
        const __half2 hh = *(const __half2*)&u;
        const float2 f = __half22float2(hh);
        const float p0 = __expf(f.x - msr.x) * msr.y;
        const float p1 = __expf(f.y - msr.x) * msr.y;
        float* orow = out1 + (size_t)gr * OUTD;
        if (c0 < OUTD)     orow[c0]     = p0;     // lanes 0..50
        if (c0 + 1 < OUTD) orow[c0 + 1] = p1;     // lanes 0..49
    }
}

extern "C" void kernel_launch(void* const* d_in, const int* in_sizes, int n_in,
                              void* d_out, int out_size, void* d_ws, size_t ws_size,
                              hipStream_t stream) {
    const float* t  = (const float*)d_in[0];
    const float* x  = (const float*)d_in[1];
    const float* w  = (const float*)d_in[2];
    const float* b  = (const float*)d_in[3];
    const int*   ng = (const int*)d_in[4];
    const int n_rows = in_sizes[0];

    float* out1       = (float*)d_out;
    float* out_interp = out1 + (size_t)n_rows * OUTD;

    const int n_blocks = (n_rows + RPB - 1) / RPB;   // 15625
    density_kernel<<<dim3(n_blocks), dim3(64), 0, stream>>>(
        t, x, w, b, ng, out1, out_interp, n_rows);
}

// Round 5
// 186.333 us; speedup vs baseline: 5.7879x; 2.3156x over previous
//
#include <hip/hip_runtime.h>
#include <hip/hip_fp16.h>
#include <math.h>

#define IND   64
#define OUTD  101
#define RPB   64
#define NCT   7          // 7 col-tiles x 16 = 112 padded cols
#define LSTRIDE 66       // fp16 units per LDS column (64 rows + 2 pad)

typedef _Float16 half8 __attribute__((ext_vector_type(8)));
typedef float    f32x4 __attribute__((ext_vector_type(4)));

__global__ __launch_bounds__(64, 3) void density_kernel(
    const float* __restrict__ t,
    const float* __restrict__ x,
    const float* __restrict__ weight,
    const float* __restrict__ bias,
    const int*   __restrict__ num_grid,
    float* __restrict__ out1,
    float* __restrict__ out_interp,
    int n_rows)
{
    __shared__ _Float16 ptile[112 * LSTRIDE];   // 14.4 KB, col-major [col][row]

    const int lane = threadIdx.x;
    const int lc   = lane & 15;        // col-in-tile / row-in-rowtile
    const int lg   = lane >> 4;        // k-group / row-group
    const int row0 = blockIdx.x * RPB;

    // ---- B fragments (weights) + bias: 56 VGPR, loaded ONCE per block ----
    // b[j] = W[k = kg*32 + lg*8 + j][col = ct*16 + lc]  (fp16)
    half8 bf[NCT][2];
    float biasv[NCT];
#pragma unroll
    for (int ct = 0; ct < NCT; ++ct) {
        int col  = ct * 16 + lc;
        int colc = (col < OUTD) ? col : (OUTD - 1);   // pad cols masked later
        biasv[ct] = bias[colc];
#pragma unroll
        for (int kg = 0; kg < 2; ++kg) {
            half8 h;
#pragma unroll
            for (int j = 0; j < 8; ++j)
                h[j] = (_Float16)weight[(kg * 32 + lg * 8 + j) * OUTD + colc];
            bf[ct][kg] = h;
        }
    }

    // interp indices (issue t load early; reads LDS after barrier)
    const float ngf = (float)num_grid[0];
    const int gr_i  = row0 + lane;
    const int grc_i = (gr_i < n_rows) ? gr_i : (n_rows - 1);
    const float tB  = t[grc_i] * ngf;
    const float Uf  = ceilf(tB);
    const float inter = 1.0f - (Uf - tB);
    float Lf = Uf - 1.0f;
    if (Lf < 0.0f) Lf += 1.0f;
    const int Li = (int)Lf, Ui = (int)Uf;

    // ---- 4 row-tiles of 16 rows ----
#pragma unroll 1
    for (int rt = 0; rt < 4; ++rt) {
        // A fragments: a[j] = x[row = rt*16+lc][k = kg*32 + lg*8 + j]
        const int grow  = row0 + rt * 16 + lc;
        const int growc = (grow < n_rows) ? grow : (n_rows - 1);
        const float* xr = x + (size_t)growc * IND + lg * 8;
        const f32x4 x0 = *(const f32x4*)(xr);
        const f32x4 x1 = *(const f32x4*)(xr + 4);
        const f32x4 x2 = *(const f32x4*)(xr + 32);
        const f32x4 x3 = *(const f32x4*)(xr + 36);
        half8 a0, a1;
#pragma unroll
        for (int i = 0; i < 4; ++i) {
            a0[i] = (_Float16)x0[i]; a0[4 + i] = (_Float16)x1[i];
            a1[i] = (_Float16)x2[i]; a1[4 + i] = (_Float16)x3[i];
        }

        // C init with bias (all 4 regs = same col), then MFMA over K=64
        f32x4 c[NCT];
#pragma unroll
        for (int ct = 0; ct < NCT; ++ct) {
            f32x4 ci = {biasv[ct], biasv[ct], biasv[ct], biasv[ct]};
            ci = __builtin_amdgcn_mfma_f32_16x16x32_f16(a0, bf[ct][0], ci, 0, 0, 0);
            ci = __builtin_amdgcn_mfma_f32_16x16x32_f16(a1, bf[ct][1], ci, 0, 0, 0);
            c[ct] = ci;
        }
        // mask pad cols (ct=6 covers 96..111; valid lc <= 4)
        if (lc > 4) {
            c[6][0] = -INFINITY; c[6][1] = -INFINITY;
            c[6][2] = -INFINITY; c[6][3] = -INFINITY;
        }

        // row-wise softmax: row = rt*16 + lg*4 + j; cols spread over 16 lanes
        float m[4], s[4];
#pragma unroll
        for (int j = 0; j < 4; ++j) {
            float mj = c[0][j];
#pragma unroll
            for (int ct = 1; ct < NCT; ++ct) mj = fmaxf(mj, c[ct][j]);
#pragma unroll
            for (int d = 1; d < 16; d <<= 1) mj = fmaxf(mj, __shfl_xor(mj, d, 64));
            m[j] = mj;
            s[j] = 0.0f;
        }
#pragma unroll
        for (int ct = 0; ct < NCT; ++ct)
#pragma unroll
            for (int j = 0; j < 4; ++j) {
                const float e = __expf(c[ct][j] - m[j]);
                c[ct][j] = e;
                s[j] += e;
            }
#pragma unroll
        for (int j = 0; j < 4; ++j) {
#pragma unroll
            for (int d = 1; d < 16; d <<= 1) s[j] += __shfl_xor(s[j], d, 64);
            float inv = __builtin_amdgcn_rcpf(s[j]);
            inv = inv * (2.0f - s[j] * inv);
            s[j] = inv;
        }
#pragma unroll
        for (int ct = 0; ct < NCT; ++ct)
#pragma unroll
            for (int j = 0; j < 4; ++j) c[ct][j] *= s[j];

        // direct out1 stores: 64B segments per 16-lane group, L2 merges
        const int rbase = row0 + rt * 16 + lg * 4;
#pragma unroll
        for (int ct = 0; ct < NCT; ++ct) {
            const int col = ct * 16 + lc;
            if (col < OUTD) {
#pragma unroll
                for (int j = 0; j < 4; ++j) {
                    const int r = rbase + j;
                    if (r < n_rows) out1[(size_t)r * OUTD + col] = c[ct][j];
                }
            }
        }

        // fp16 p -> LDS (col-major) for the interp gather
        const int r0l = rt * 16 + lg * 4;
#pragma unroll
        for (int ct = 0; ct < NCT; ++ct) {
            const int col = ct * 16 + lc;
            __half2* dst = (__half2*)&ptile[col * LSTRIDE + r0l];
            dst[0] = __floats2half2_rn(c[ct][0], c[ct][1]);
            dst[1] = __floats2half2_rn(c[ct][2], c[ct][3]);
        }
    }

    __syncthreads();

    // ---- interp: lane = row, gather 2 fp16 from own row's columns ----
    const float Lv = (float)ptile[Li * LSTRIDE + lane];
    const float Uv = (float)ptile[Ui * LSTRIDE + lane];
    if (gr_i < n_rows) out_interp[gr_i] = Lv + (Uv - Lv) * inter;
}

extern "C" void kernel_launch(void* const* d_in, const int* in_sizes, int n_in,
                              void* d_out, int out_size, void* d_ws, size_t ws_size,
                              hipStream_t stream) {
    const float* t  = (const float*)d_in[0];
    const float* x  = (const float*)d_in[1];
    const float* w  = (const float*)d_in[2];
    const float* b  = (const float*)d_in[3];
    const int*   ng = (const int*)d_in[4];
    const int n_rows = in_sizes[0];

    float* out1       = (float*)d_out;
    float* out_interp = out1 + (size_t)n_rows * OUTD;

    const int n_blocks = (n_rows + RPB - 1) / RPB;   // 15625
    density_kernel<<<dim3(n_blocks), dim3(64), 0, stream>>>(
        t, x, w, b, ng, out1, out_interp, n_rows);
}